// Round 5
// baseline (903.450 us; speedup 1.0000x reference)
//
#include <hip/hip_runtime.h>
#include <math.h>

#define TAU_F 0.6f

typedef short short8 __attribute__((ext_vector_type(8)));
typedef float floatx4 __attribute__((ext_vector_type(4)));

__device__ __forceinline__ ushort f2bf(float f) {
    unsigned u = __float_as_uint(f);
    u += 0x7FFF + ((u >> 16) & 1);
    return (ushort)(u >> 16);
}
__device__ __forceinline__ float bf2f(ushort h) {
    return __uint_as_float(((unsigned)h) << 16);
}
__device__ __forceinline__ int swz(int row, int j, int mask) { return j ^ (row & mask); }

// Stage a tile from global into LDS with XOR-chunk swizzle via global_load_lds (16B).
template<int CPR, int SC>
__device__ __forceinline__ void stage_swz(ushort* lds, const char* g, int rowstride_bytes,
                                          int w, int lane)
{
    #pragma unroll
    for (int p = 0; p < (SC + 3) / 4; ++p) {
        int sc = w + p * 4;
        if (SC % 4 != 0 && sc >= SC) break;
        int LC = sc * 64 + lane;
        int r = LC / CPR;
        int s = LC % CPR;
        int j = s ^ (r & (CPR - 1));
        const char* gp = g + (size_t)r * rowstride_bytes + j * 16;
        __builtin_amdgcn_global_load_lds(
            (const __attribute__((address_space(1))) void*)gp,
            (__attribute__((address_space(3))) void*)((char*)lds + sc * 1024), 16, 0, 0);
    }
}

// ===================== MFMA NT GEMM: C[M,N] = A[M,K] * Bt[N,K]^T + bias =====================
template<bool SPLIT>
__global__ __launch_bounds__(256) void gemm_nt_kernel(
    const ushort* __restrict__ Ah, const ushort* __restrict__ Al, int lda,
    const ushort* __restrict__ Bh, const ushort* __restrict__ Bl, int ldb,
    const float* __restrict__ bias, float* __restrict__ C, int ldc, int K)
{
    __shared__ __align__(16) ushort smem[(SPLIT ? 4 : 2) * 128 * 32];
    ushort* As_h = smem;
    ushort* Bs_h = smem + 128 * 32;
    ushort* As_l = SPLIT ? smem + 2 * 128 * 32 : nullptr;
    ushort* Bs_l = SPLIT ? smem + 3 * 128 * 32 : nullptr;
    const int tid = threadIdx.x;
    const int w = tid >> 6, lane = tid & 63;
    const int quad = lane >> 4, c15 = lane & 15;
    const int wm = w >> 1, wn = w & 1;
    const int bm = blockIdx.y * 128, bn = blockIdx.x * 128;

    floatx4 acc[4][4];
    #pragma unroll
    for (int i = 0; i < 4; i++)
        #pragma unroll
        for (int j = 0; j < 4; j++) acc[i][j] = (floatx4){0.f, 0.f, 0.f, 0.f};

    const char* Ab = (const char*)(Ah + (size_t)bm * lda);
    const char* Bb = (const char*)(Bh + (size_t)bn * ldb);
    const char* Alb = SPLIT ? (const char*)(Al + (size_t)bm * lda) : nullptr;
    const char* Blb = SPLIT ? (const char*)(Bl + (size_t)bn * ldb) : nullptr;

    for (int k0 = 0; k0 < K; k0 += 32) {
        stage_swz<4, 8>(As_h, Ab + k0 * 2, lda * 2, w, lane);
        stage_swz<4, 8>(Bs_h, Bb + k0 * 2, ldb * 2, w, lane);
        if constexpr (SPLIT) {
            stage_swz<4, 8>(As_l, Alb + k0 * 2, lda * 2, w, lane);
            stage_swz<4, 8>(Bs_l, Blb + k0 * 2, ldb * 2, w, lane);
        }
        __syncthreads();
        short8 a_h[4], b_h[4], a_l[4], b_l[4];
        #pragma unroll
        for (int mt = 0; mt < 4; mt++) {
            int row = wm * 64 + mt * 16 + c15;
            a_h[mt] = *(const short8*)&As_h[row * 32 + swz(row, quad, 3) * 8];
            if constexpr (SPLIT)
                a_l[mt] = *(const short8*)&As_l[row * 32 + swz(row, quad, 3) * 8];
        }
        #pragma unroll
        for (int nt = 0; nt < 4; nt++) {
            int row = wn * 64 + nt * 16 + c15;
            b_h[nt] = *(const short8*)&Bs_h[row * 32 + swz(row, quad, 3) * 8];
            if constexpr (SPLIT)
                b_l[nt] = *(const short8*)&Bs_l[row * 32 + swz(row, quad, 3) * 8];
        }
        #pragma unroll
        for (int mt = 0; mt < 4; mt++)
            #pragma unroll
            for (int nt = 0; nt < 4; nt++)
                acc[mt][nt] = __builtin_amdgcn_mfma_f32_16x16x32_bf16(a_h[mt], b_h[nt], acc[mt][nt], 0, 0, 0);
        if constexpr (SPLIT) {
            #pragma unroll
            for (int mt = 0; mt < 4; mt++)
                #pragma unroll
                for (int nt = 0; nt < 4; nt++)
                    acc[mt][nt] = __builtin_amdgcn_mfma_f32_16x16x32_bf16(a_h[mt], b_l[nt], acc[mt][nt], 0, 0, 0);
            #pragma unroll
            for (int mt = 0; mt < 4; mt++)
                #pragma unroll
                for (int nt = 0; nt < 4; nt++)
                    acc[mt][nt] = __builtin_amdgcn_mfma_f32_16x16x32_bf16(a_l[mt], b_h[nt], acc[mt][nt], 0, 0, 0);
        }
        __syncthreads();
    }
    #pragma unroll
    for (int mt = 0; mt < 4; mt++)
        #pragma unroll
        for (int nt = 0; nt < 4; nt++) {
            int col = bn + wn * 64 + nt * 16 + c15;
            float bs = bias ? bias[col] : 0.f;
            #pragma unroll
            for (int r = 0; r < 4; r++) {
                int row = bm + wm * 64 + mt * 16 + quad * 4 + r;
                C[(size_t)row * ldc + col] = acc[mt][nt][r] + bs;
            }
        }
}

// ===================== sim GEMM (bf16) with fused per-row max/argmax =====================
__global__ __launch_bounds__(256) void simmax_mfma(
    const ushort* __restrict__ A, const ushort* __restrict__ B,
    float* __restrict__ pval, int* __restrict__ pidx)
{
    __shared__ __align__(16) ushort As_h[128 * 32];
    __shared__ __align__(16) ushort Bs_h[128 * 32];
    __shared__ float redv[128][2];
    __shared__ int   redi[128][2];
    const int tid = threadIdx.x;
    const int w = tid >> 6, lane = tid & 63;
    const int quad = lane >> 4, c15 = lane & 15;
    const int wm = w >> 1, wn = w & 1;
    const int bm = blockIdx.y * 128, bn = blockIdx.x * 128;

    floatx4 acc[4][4];
    #pragma unroll
    for (int i = 0; i < 4; i++)
        #pragma unroll
        for (int j = 0; j < 4; j++) acc[i][j] = (floatx4){0.f, 0.f, 0.f, 0.f};

    const char* Ab = (const char*)(A + (size_t)bm * 1024);
    const char* Bb = (const char*)(B + (size_t)bn * 1024);

    for (int k0 = 0; k0 < 1024; k0 += 32) {
        stage_swz<4, 8>(As_h, Ab + k0 * 2, 2048, w, lane);
        stage_swz<4, 8>(Bs_h, Bb + k0 * 2, 2048, w, lane);
        __syncthreads();
        short8 a_h[4], b_h[4];
        #pragma unroll
        for (int mt = 0; mt < 4; mt++) {
            int row = wm * 64 + mt * 16 + c15;
            a_h[mt] = *(const short8*)&As_h[row * 32 + swz(row, quad, 3) * 8];
        }
        #pragma unroll
        for (int nt = 0; nt < 4; nt++) {
            int row = wn * 64 + nt * 16 + c15;
            b_h[nt] = *(const short8*)&Bs_h[row * 32 + swz(row, quad, 3) * 8];
        }
        #pragma unroll
        for (int mt = 0; mt < 4; mt++)
            #pragma unroll
            for (int nt = 0; nt < 4; nt++)
                acc[mt][nt] = __builtin_amdgcn_mfma_f32_16x16x32_bf16(a_h[mt], b_h[nt], acc[mt][nt], 0, 0, 0);
        __syncthreads();
    }
    #pragma unroll
    for (int mt = 0; mt < 4; mt++)
        #pragma unroll
        for (int r = 0; r < 4; r++) {
            float bv = -1e30f; int bi = 0;
            #pragma unroll
            for (int nt = 0; nt < 4; nt++) {
                float v = acc[mt][nt][r];
                int col = bn + wn * 64 + nt * 16 + c15;
                if (v > bv) { bv = v; bi = col; }
            }
            #pragma unroll
            for (int m = 1; m < 16; m <<= 1) {
                float ov = __shfl_xor(bv, m, 64);
                int   oi = __shfl_xor(bi, m, 64);
                if (ov > bv || (ov == bv && oi < bi)) { bv = ov; bi = oi; }
            }
            if (c15 == 0) {
                int row = wm * 64 + mt * 16 + quad * 4 + r;
                redv[row][wn] = bv; redi[row][wn] = bi;
            }
        }
    __syncthreads();
    if (tid < 128) {
        float v0 = redv[tid][0], v1 = redv[tid][1];
        int   i0 = redi[tid][0], i1 = redi[tid][1];
        bool t = (v1 > v0) || (v1 == v0 && i1 < i0);
        pval[(size_t)blockIdx.x * 4096 + bm + tid] = t ? v1 : v0;
        pidx[(size_t)blockIdx.x * 4096 + bm + tid] = t ? i1 : i0;
    }
}

// fused reduce for both halves + ssum zeroing
__global__ void simreduce2_kernel(const float* __restrict__ pval, const int* __restrict__ pidx,
                                  float* __restrict__ bv0, int* __restrict__ bi0,
                                  float* __restrict__ bv1, int* __restrict__ bi1,
                                  float* __restrict__ ssum)
{
    if (blockIdx.x == 0 && threadIdx.x < 2) ssum[threadIdx.x] = 0.f;
    const int n = blockIdx.x * 256 + threadIdx.x;
    float best = -1e30f; int besti = 0x7fffffff;
    for (int c = 0; c < 32; c++) {
        float v = pval[(size_t)c * 4096 + n]; int ix = pidx[(size_t)c * 4096 + n];
        if (v > best || (v == best && ix < besti)) { best = v; besti = ix; }
    }
    bv0[n] = best; bi0[n] = besti;
    best = -1e30f; besti = 0x7fffffff;
    for (int c = 32; c < 64; c++) {
        float v = pval[(size_t)c * 4096 + n]; int ix = pidx[(size_t)c * 4096 + n];
        if (v > best || (v == best && ix < besti)) { best = v; besti = ix; }
    }
    bv1[n] = best; bi1[n] = besti - 4096;
}

// ===================== conversions =====================
// plain fp32 -> bf16
__global__ __launch_bounds__(256) void xconv_kernel(const float* __restrict__ s,
                                                    ushort* __restrict__ dh)
{
    const int i = blockIdx.x * 256 + threadIdx.x;
    float4 v = ((const float4*)s)[i];
    ushort4 h;
    h.x = f2bf(v.x); h.y = f2bf(v.y); h.z = f2bf(v.z); h.w = f2bf(v.w);
    ((ushort4*)dh)[i] = h;
}

__global__ __launch_bounds__(256) void wtrans_kernel(const float* __restrict__ src, int R, int Cc,
                                                     ushort* __restrict__ dh, ushort* __restrict__ dl)
{
    __shared__ float t[64][65];
    const int tid = threadIdx.x;
    const int c0 = blockIdx.x * 64, r0 = blockIdx.y * 64;
    #pragma unroll
    for (int i = 0; i < 16; i++) {
        int lin = i * 256 + tid;
        int rr = lin >> 6, cc = lin & 63;
        t[rr][cc] = src[(size_t)(r0 + rr) * Cc + c0 + cc];
    }
    __syncthreads();
    #pragma unroll
    for (int i = 0; i < 16; i++) {
        int lin = i * 256 + tid;
        int cc2 = lin >> 6, rr2 = lin & 63;
        float v = t[rr2][cc2];
        ushort h = f2bf(v);
        dh[(size_t)(c0 + cc2) * R + r0 + rr2] = h;
        if (dl) dl[(size_t)(c0 + cc2) * R + r0 + rr2] = f2bf(v - bf2f(h));
    }
}

// q: mh_rms -> bf16 [h][n][d]. one wave per (n,h)
__global__ __launch_bounds__(256) void qconv_kernel(const float* __restrict__ QKV,
                                                    const float* __restrict__ gamma_q,
                                                    ushort* __restrict__ Qh)
{
    const int wg = blockIdx.x * 4 + (threadIdx.x >> 6);
    const int lane = threadIdx.x & 63;
    const int n = wg >> 4, h = wg & 15;
    float x = QKV[(size_t)n * 3072 + h * 64 + lane];
    float ss = x * x;
    #pragma unroll
    for (int off = 32; off; off >>= 1) ss += __shfl_xor(ss, off, 64);
    float v = x * (8.0f * gamma_q[h * 64 + lane] / fmaxf(sqrtf(ss), 1e-12f));
    Qh[((size_t)h * 4096 + n) * 64 + lane] = f2bf(v);
}

// l2-normalize rows -> bf16, three sources in one launch. grid (4096, 3)
__global__ __launch_bounds__(256) void kbn3_kernel(const float* __restrict__ QKV,
                                                   const float* __restrict__ k0,
                                                   const float* __restrict__ k1,
                                                   ushort* __restrict__ kbn,
                                                   ushort* __restrict__ k01bn)
{
    const int n = blockIdx.x, t = threadIdx.x, y = blockIdx.y;
    const float* src; int ld; ushort* dst;
    if (y == 0)      { src = QKV + 1024; ld = 3072; dst = kbn; }
    else if (y == 1) { src = k0; ld = 1024; dst = k01bn; }
    else             { src = k1; ld = 1024; dst = k01bn + (size_t)4096 * 1024; }
    float4 v = *(const float4*)(src + (size_t)n * ld + 4 * t);
    float ss = v.x * v.x + v.y * v.y + v.z * v.z + v.w * v.w;
    #pragma unroll
    for (int off = 32; off; off >>= 1) ss += __shfl_xor(ss, off, 64);
    __shared__ float wsum[4];
    if ((t & 63) == 0) wsum[t >> 6] = ss;
    __syncthreads();
    float inv = 1.0f / fmaxf(sqrtf(wsum[0] + wsum[1] + wsum[2] + wsum[3]), 1e-12f);
    ushort4 o;
    o.x = f2bf(v.x * inv); o.y = f2bf(v.y * inv);
    o.z = f2bf(v.z * inv); o.w = f2bf(v.w * inv);
    *(ushort4*)(dst + (size_t)n * 1024 + 4 * t) = o;
}

// combine + per-head mh_rms(k) -> CKh [16][4096][64]; CV fp32 + sumsqs
__global__ __launch_bounds__(256) void combine_kernel(
    const float* __restrict__ QKV,
    const float* __restrict__ k0, const float* __restrict__ v0,
    const float* __restrict__ k1, const float* __restrict__ v1,
    const float* __restrict__ bv0, const int* __restrict__ bi0,
    const float* __restrict__ bv1, const int* __restrict__ bi1,
    const float* __restrict__ gamma_k,
    ushort* __restrict__ CKh,
    float* __restrict__ CV, float* __restrict__ ss)
{
    const int n = blockIdx.x, t = threadIdx.x;
    const bool va0 = bv0[n] > TAU_F; const int i0 = bi0[n];
    const bool va1 = bv1[n] > TAU_F; const int i1 = bi1[n];
    float4 kf = ((const float4*)(QKV + (size_t)n * 3072 + 1024))[t];
    float4 vf = ((const float4*)(QKV + (size_t)n * 3072 + 2048))[t];
    float4 kg0 = va0 ? ((const float4*)(k0 + (size_t)i0 * 1024))[t] : kf;
    float4 vg0 = va0 ? ((const float4*)(v0 + (size_t)i0 * 1024))[t] : vf;
    float4 kg1 = va1 ? ((const float4*)(k1 + (size_t)i1 * 1024))[t] : kf;
    float4 vg1 = va1 ? ((const float4*)(v1 + (size_t)i1 * 1024))[t] : vf;
    float4 ck, cv;
    ck.x = 0.5f * kg0.x + 0.5f * kg1.x + kf.x;
    ck.y = 0.5f * kg0.y + 0.5f * kg1.y + kf.y;
    ck.z = 0.5f * kg0.z + 0.5f * kg1.z + kf.z;
    ck.w = 0.5f * kg0.w + 0.5f * kg1.w + kf.w;
    cv.x = 0.5f * vg0.x + 0.5f * vg1.x + vf.x;
    cv.y = 0.5f * vg0.y + 0.5f * vg1.y + vf.y;
    cv.z = 0.5f * vg0.z + 0.5f * vg1.z + vf.z;
    cv.w = 0.5f * vg0.w + 0.5f * vg1.w + vf.w;
    ((float4*)(CV + (size_t)n * 1024))[t] = cv;
    float s0 = vf.x * vf.x + vf.y * vf.y + vf.z * vf.z + vf.w * vf.w;
    float s1 = cv.x * cv.x + cv.y * cv.y + cv.z * cv.z + cv.w * cv.w;
    #pragma unroll
    for (int off = 32; off; off >>= 1) {
        s0 += __shfl_xor(s0, off, 64);
        s1 += __shfl_xor(s1, off, 64);
    }
    __shared__ float w0[4], w1[4];
    if ((t & 63) == 0) { w0[t >> 6] = s0; w1[t >> 6] = s1; }
    float hs = ck.x * ck.x + ck.y * ck.y + ck.z * ck.z + ck.w * ck.w;
    #pragma unroll
    for (int m = 1; m < 16; m <<= 1) hs += __shfl_xor(hs, m, 64);
    float inv = 8.0f / fmaxf(sqrtf(hs), 1e-12f);
    float4 g = ((const float4*)gamma_k)[t];
    const int h = t >> 4;
    size_t o = ((size_t)h * 4096 + n) * 64 + 4 * (t & 15);
    ushort4 hh;
    hh.x = f2bf(ck.x * inv * g.x);
    hh.y = f2bf(ck.y * inv * g.y);
    hh.z = f2bf(ck.z * inv * g.z);
    hh.w = f2bf(ck.w * inv * g.w);
    *(ushort4*)(CKh + o) = hh;
    __syncthreads();
    if (t == 0) {
        atomicAdd(ss + 0, w0[0] + w0[1] + w0[2] + w0[3]);
        atomicAdd(ss + 1, w1[0] + w1[1] + w1[2] + w1[3]);
    }
}

// CV fp32 [4096][1024] --(*sv)--> Vt bf16 [1024][4096]
__global__ __launch_bounds__(256) void vt_kernel(const float* __restrict__ CV,
                                                 const float* __restrict__ ss,
                                                 ushort* __restrict__ Vt)
{
    __shared__ float t[64][65];
    const float sv = sqrtf(ss[0] / ss[1]);
    const int tid = threadIdx.x;
    const int n0 = blockIdx.x * 64, d0 = blockIdx.y * 64;
    #pragma unroll
    for (int i = 0; i < 16; i++) {
        int lin = i * 256 + tid;
        int r = lin >> 6, c = lin & 63;
        t[r][c] = CV[(size_t)(n0 + r) * 1024 + d0 + c];
    }
    __syncthreads();
    #pragma unroll
    for (int i = 0; i < 16; i++) {
        int lin = i * 256 + tid;
        int dr = lin >> 6, nc = lin & 63;
        Vt[(size_t)(d0 + dr) * 4096 + n0 + nc] = f2bf(t[nc][dr] * sv);
    }
}

// ===================== flash attention, MFMA, barrier-free fixed-max =====================
// grid (64 q-tiles, 16 heads), 256 threads = 4 independent waves, 16 q-rows each.
// Logit bound: |q|=|k|=8 per head (gamma=1 rms) => s=q.k/8 in [-8.2,8.2]; fixed max 8.5.
// p = exp(s - 8.5) <= 1 always; softmax identical after normalization. No online-max
// state, no alpha rescale, no cross-wave data => NO barriers. K/V fragments loaded
// directly from global in MFMA B-layout (L1/L2 cached); LDS only for wave-private P.
__global__ __launch_bounds__(256, 4) void attn_mfma(
    const ushort* __restrict__ Qh,   // [16][4096][64]
    const ushort* __restrict__ Kh,   // [16][4096][64]
    const ushort* __restrict__ Vt,   // [16*64][4096]
    ushort* __restrict__ Hb)         // [4096][1024]
{
    __shared__ __align__(16) ushort Ps[64 * 128];   // 16 KB, wave-private rows
    const int h = blockIdx.y;
    const int n0 = blockIdx.x * 64;
    const int tid = threadIdx.x;
    const int w = tid >> 6, lane = tid & 63;
    const int quad = lane >> 4, c15 = lane & 15;

    short8 qf[2];
    #pragma unroll
    for (int kh = 0; kh < 2; kh++)
        qf[kh] = *(const short8*)(Qh + ((size_t)h * 4096 + n0 + w * 16 + c15) * 64 + kh * 32 + quad * 8);

    const ushort* Kbase = Kh + (size_t)h * 4096 * 64;
    const ushort* Vbase = Vt + (size_t)h * 64 * 4096;

    floatx4 po[4];
    #pragma unroll
    for (int nt = 0; nt < 4; nt++) po[nt] = (floatx4){0.f, 0.f, 0.f, 0.f};
    float lac[4] = {0.f, 0.f, 0.f, 0.f};

    for (int it = 0; it < 32; ++it) {
        const int m0 = it * 128;
        // S = Q K^T, K frags straight from global (B-layout)
        floatx4 s[8];
        #pragma unroll
        for (int nt = 0; nt < 8; nt++) {
            const ushort* kp = Kbase + (size_t)(m0 + nt * 16 + c15) * 64 + quad * 8;
            short8 ka = *(const short8*)kp;
            short8 kb = *(const short8*)(kp + 32);
            floatx4 z = (floatx4){0.f, 0.f, 0.f, 0.f};
            z = __builtin_amdgcn_mfma_f32_16x16x32_bf16(qf[0], ka, z, 0, 0, 0);
            z = __builtin_amdgcn_mfma_f32_16x16x32_bf16(qf[1], kb, z, 0, 0, 0);
            s[nt] = z;
        }
        // fixed-max softmax numerators -> Ps (A-layout via swizzled LDS)
        const int prow0 = w * 16 + quad * 4;
        #pragma unroll
        for (int nt = 0; nt < 8; nt++) {
            int col = nt * 16 + c15;
            #pragma unroll
            for (int r = 0; r < 4; r++) {
                float p = __expf(fmaf(s[nt][r], 0.125f, -8.5f));
                lac[r] += p;
                int pr = prow0 + r;
                Ps[pr * 128 + swz(pr, col >> 3, 15) * 8 + (col & 7)] = f2bf(p);
            }
        }
        // O += P V, V frags straight from global (B-layout)
        const int pr2 = w * 16 + c15;
        #pragma unroll
        for (int kb2 = 0; kb2 < 4; kb2++) {
            short8 pa = *(const short8*)&Ps[pr2 * 128 + swz(pr2, kb2 * 4 + quad, 15) * 8];
            #pragma unroll
            for (int nt = 0; nt < 4; nt++) {
                const ushort* vp = Vbase + (size_t)(nt * 16 + c15) * 4096 + m0 + kb2 * 32 + quad * 8;
                short8 vb = *(const short8*)vp;
                po[nt] = __builtin_amdgcn_mfma_f32_16x16x32_bf16(pa, vb, po[nt], 0, 0, 0);
            }
        }
    }
    // final l reduce (16 lanes per row) + normalize + store
    #pragma unroll
    for (int r = 0; r < 4; r++) {
        float l = lac[r];
        #pragma unroll
        for (int m = 1; m < 16; m <<= 1) l += __shfl_xor(l, m, 64);
        float inv = 1.0f / l;
        int row = n0 + w * 16 + quad * 4 + r;
        #pragma unroll
        for (int nt = 0; nt < 4; nt++)
            Hb[(size_t)row * 1024 + h * 64 + nt * 16 + c15] = f2bf(po[nt][r] * inv);
    }
}

// ===================== launcher =====================
extern "C" void kernel_launch(void* const* d_in, const int* in_sizes, int n_in,
                              void* d_out, int out_size, void* d_ws, size_t ws_size,
                              hipStream_t stream)
{
    const float* x       = (const float*)d_in[0];
    const float* k0      = (const float*)d_in[1];
    const float* v0      = (const float*)d_in[2];
    const float* k1      = (const float*)d_in[3];
    const float* v1      = (const float*)d_in[4];
    const float* W_qkv   = (const float*)d_in[5];
    const float* b_qkv   = (const float*)d_in[6];
    const float* gamma_q = (const float*)d_in[7];
    const float* gamma_k = (const float*)d_in[8];
    const float* W_out   = (const float*)d_in[9];
    const float* b_out   = (const float*)d_in[10];
    float* out = (float*)d_out;

    char* W = (char*)d_ws;
    // Region A (0..48M): QKV fp32; after combine reused for Vt + Hb
    float*  QKV = (float*)(W + 0);
    ushort* Vt  = (ushort*)(W + 0);
    ushort* Hb  = (ushort*)(W + 8388608);
    // Region B (48M..56M): Qb
    ushort* Qbh = (ushort*)(W + 50331648);
    // Region C (64M..96M): phased
    ushort* xh   = (ushort*)(W + 67108864);
    ushort* Wqh  = (ushort*)(W + 67108864 + 8388608);
    ushort* kbn  = (ushort*)(W + 67108864);
    ushort* k01bn= (ushort*)(W + 67108864 + 8388608);
    float*  pval = (float*)(W + 67108864 + 25165824);
    int*    pidx = (int*)  (W + 67108864 + 26214400);
    float*  CV   = (float*)(W + 67108864);
    ushort* CKh  = (ushort*)(W + 67108864 + 16777216);
    ushort* Wob  = (ushort*)(W + 67108864);             // after CV dead
    // Region D (96M..): small
    float* bv0  = (float*)(W + 100663296);
    int*   bi0  = (int*)  (W + 100663296 + 16384);
    float* bv1  = (float*)(W + 100663296 + 32768);
    int*   bi1  = (int*)  (W + 100663296 + 49152);
    float* ssum = (float*)(W + 100663296 + 65536);

    // 1. convert inputs for QKV GEMM (plain bf16)
    xconv_kernel<<<4096, 256, 0, stream>>>(x, xh);
    wtrans_kernel<<<dim3(48, 16), 256, 0, stream>>>(W_qkv, 1024, 3072, Wqh, nullptr);
    // 2. QKV = x @ W_qkv + b (plain bf16)
    gemm_nt_kernel<false><<<dim3(24, 32), 256, 0, stream>>>(xh, nullptr, 1024, Wqh, nullptr, 1024,
                                                            b_qkv, QKV, 3072, 1024);
    // 3. q -> mh_rms -> bf16 [h][n][d]
    qconv_kernel<<<16384, 256, 0, stream>>>(QKV, gamma_q, Qbh);
    // 4. normalized bf16 copies for sim
    kbn3_kernel<<<dim3(4096, 3), 256, 0, stream>>>(QKV, k0, k1, kbn, k01bn);
    // 5. sim + top-1 over concatenated [k0;k1]
    simmax_mfma<<<dim3(64, 32), 256, 0, stream>>>(kbn, k01bn, pval, pidx);
    simreduce2_kernel<<<16, 256, 0, stream>>>(pval, pidx, bv0, bi0, bv1, bi1, ssum);
    // 6. combine (+mh_rms k fused; sk cancels) -> CKh, CV fp32, sumsqs
    combine_kernel<<<4096, 256, 0, stream>>>(QKV, k0, v0, k1, v1, bv0, bi0, bv1, bi1,
                                             gamma_k, CKh, CV, ssum);
    // 7. V: scale by sv + transpose -> Vt bf16 [1024][4096]
    vt_kernel<<<dim3(64, 16), 256, 0, stream>>>(CV, ssum, Vt);
    // 8. W_out transpose -> bf16 (CV dead now)
    wtrans_kernel<<<dim3(16, 16), 256, 0, stream>>>(W_out, 1024, 1024, Wob, nullptr);
    // 9. flash attention (barrier-free, fixed-max softmax)
    attn_mfma<<<dim3(64, 16), 256, 0, stream>>>(Qbh, CKh, Vt, Hb);
    // 10. out = Hb @ W_out^T + b_out (plain bf16)
    gemm_nt_kernel<false><<<dim3(8, 32), 256, 0, stream>>>(Hb, nullptr, 1024, Wob, nullptr, 1024,
                                                           b_out, out, 1024, 1024);
}

// Round 6
// 583.449 us; speedup vs baseline: 1.5485x; 1.5485x over previous
//
#include <hip/hip_runtime.h>
#include <math.h>

#define TAU_F 0.6f

typedef short short8 __attribute__((ext_vector_type(8)));
typedef float floatx4 __attribute__((ext_vector_type(4)));

__device__ __forceinline__ ushort f2bf(float f) {
    unsigned u = __float_as_uint(f);
    u += 0x7FFF + ((u >> 16) & 1);
    return (ushort)(u >> 16);
}
__device__ __forceinline__ float bf2f(ushort h) {
    return __uint_as_float(((unsigned)h) << 16);
}
__device__ __forceinline__ int swz(int row, int j, int mask) { return j ^ (row & mask); }

// Stage a tile from global into LDS with XOR-chunk swizzle via global_load_lds (16B).
template<int CPR, int SC>
__device__ __forceinline__ void stage_swz(ushort* lds, const char* g, int rowstride_bytes,
                                          int w, int lane)
{
    #pragma unroll
    for (int p = 0; p < (SC + 3) / 4; ++p) {
        int sc = w + p * 4;
        if (SC % 4 != 0 && sc >= SC) break;
        int LC = sc * 64 + lane;
        int r = LC / CPR;
        int s = LC % CPR;
        int j = s ^ (r & (CPR - 1));
        const char* gp = g + (size_t)r * rowstride_bytes + j * 16;
        __builtin_amdgcn_global_load_lds(
            (const __attribute__((address_space(1))) void*)gp,
            (__attribute__((address_space(3))) void*)((char*)lds + sc * 1024), 16, 0, 0);
    }
}

// ===================== MFMA NT GEMM: C[M,N] = A[M,K] * Bt[N,K]^T + bias =====================
template<bool SPLIT>
__global__ __launch_bounds__(256) void gemm_nt_kernel(
    const ushort* __restrict__ Ah, const ushort* __restrict__ Al, int lda,
    const ushort* __restrict__ Bh, const ushort* __restrict__ Bl, int ldb,
    const float* __restrict__ bias, float* __restrict__ C, int ldc, int K)
{
    __shared__ __align__(16) ushort smem[(SPLIT ? 4 : 2) * 128 * 32];
    ushort* As_h = smem;
    ushort* Bs_h = smem + 128 * 32;
    ushort* As_l = SPLIT ? smem + 2 * 128 * 32 : nullptr;
    ushort* Bs_l = SPLIT ? smem + 3 * 128 * 32 : nullptr;
    const int tid = threadIdx.x;
    const int w = tid >> 6, lane = tid & 63;
    const int quad = lane >> 4, c15 = lane & 15;
    const int wm = w >> 1, wn = w & 1;
    const int bm = blockIdx.y * 128, bn = blockIdx.x * 128;

    floatx4 acc[4][4];
    #pragma unroll
    for (int i = 0; i < 4; i++)
        #pragma unroll
        for (int j = 0; j < 4; j++) acc[i][j] = (floatx4){0.f, 0.f, 0.f, 0.f};

    const char* Ab = (const char*)(Ah + (size_t)bm * lda);
    const char* Bb = (const char*)(Bh + (size_t)bn * ldb);
    const char* Alb = SPLIT ? (const char*)(Al + (size_t)bm * lda) : nullptr;
    const char* Blb = SPLIT ? (const char*)(Bl + (size_t)bn * ldb) : nullptr;

    for (int k0 = 0; k0 < K; k0 += 32) {
        stage_swz<4, 8>(As_h, Ab + k0 * 2, lda * 2, w, lane);
        stage_swz<4, 8>(Bs_h, Bb + k0 * 2, ldb * 2, w, lane);
        if constexpr (SPLIT) {
            stage_swz<4, 8>(As_l, Alb + k0 * 2, lda * 2, w, lane);
            stage_swz<4, 8>(Bs_l, Blb + k0 * 2, ldb * 2, w, lane);
        }
        __syncthreads();
        short8 a_h[4], b_h[4], a_l[4], b_l[4];
        #pragma unroll
        for (int mt = 0; mt < 4; mt++) {
            int row = wm * 64 + mt * 16 + c15;
            a_h[mt] = *(const short8*)&As_h[row * 32 + swz(row, quad, 3) * 8];
            if constexpr (SPLIT)
                a_l[mt] = *(const short8*)&As_l[row * 32 + swz(row, quad, 3) * 8];
        }
        #pragma unroll
        for (int nt = 0; nt < 4; nt++) {
            int row = wn * 64 + nt * 16 + c15;
            b_h[nt] = *(const short8*)&Bs_h[row * 32 + swz(row, quad, 3) * 8];
            if constexpr (SPLIT)
                b_l[nt] = *(const short8*)&Bs_l[row * 32 + swz(row, quad, 3) * 8];
        }
        #pragma unroll
        for (int mt = 0; mt < 4; mt++)
            #pragma unroll
            for (int nt = 0; nt < 4; nt++)
                acc[mt][nt] = __builtin_amdgcn_mfma_f32_16x16x32_bf16(a_h[mt], b_h[nt], acc[mt][nt], 0, 0, 0);
        if constexpr (SPLIT) {
            #pragma unroll
            for (int mt = 0; mt < 4; mt++)
                #pragma unroll
                for (int nt = 0; nt < 4; nt++)
                    acc[mt][nt] = __builtin_amdgcn_mfma_f32_16x16x32_bf16(a_h[mt], b_l[nt], acc[mt][nt], 0, 0, 0);
            #pragma unroll
            for (int mt = 0; mt < 4; mt++)
                #pragma unroll
                for (int nt = 0; nt < 4; nt++)
                    acc[mt][nt] = __builtin_amdgcn_mfma_f32_16x16x32_bf16(a_l[mt], b_h[nt], acc[mt][nt], 0, 0, 0);
        }
        __syncthreads();
    }
    #pragma unroll
    for (int mt = 0; mt < 4; mt++)
        #pragma unroll
        for (int nt = 0; nt < 4; nt++) {
            int col = bn + wn * 64 + nt * 16 + c15;
            float bs = bias ? bias[col] : 0.f;
            #pragma unroll
            for (int r = 0; r < 4; r++) {
                int row = bm + wm * 64 + mt * 16 + quad * 4 + r;
                C[(size_t)row * ldc + col] = acc[mt][nt][r] + bs;
            }
        }
}

// ===================== sim GEMM (bf16) with fused per-row max/argmax =====================
__global__ __launch_bounds__(256) void simmax_mfma(
    const ushort* __restrict__ A, const ushort* __restrict__ B,
    float* __restrict__ pval, int* __restrict__ pidx)
{
    __shared__ __align__(16) ushort As_h[128 * 32];
    __shared__ __align__(16) ushort Bs_h[128 * 32];
    __shared__ float redv[128][2];
    __shared__ int   redi[128][2];
    const int tid = threadIdx.x;
    const int w = tid >> 6, lane = tid & 63;
    const int quad = lane >> 4, c15 = lane & 15;
    const int wm = w >> 1, wn = w & 1;
    const int bm = blockIdx.y * 128, bn = blockIdx.x * 128;

    floatx4 acc[4][4];
    #pragma unroll
    for (int i = 0; i < 4; i++)
        #pragma unroll
        for (int j = 0; j < 4; j++) acc[i][j] = (floatx4){0.f, 0.f, 0.f, 0.f};

    const char* Ab = (const char*)(A + (size_t)bm * 1024);
    const char* Bb = (const char*)(B + (size_t)bn * 1024);

    for (int k0 = 0; k0 < 1024; k0 += 32) {
        stage_swz<4, 8>(As_h, Ab + k0 * 2, 2048, w, lane);
        stage_swz<4, 8>(Bs_h, Bb + k0 * 2, 2048, w, lane);
        __syncthreads();
        short8 a_h[4], b_h[4];
        #pragma unroll
        for (int mt = 0; mt < 4; mt++) {
            int row = wm * 64 + mt * 16 + c15;
            a_h[mt] = *(const short8*)&As_h[row * 32 + swz(row, quad, 3) * 8];
        }
        #pragma unroll
        for (int nt = 0; nt < 4; nt++) {
            int row = wn * 64 + nt * 16 + c15;
            b_h[nt] = *(const short8*)&Bs_h[row * 32 + swz(row, quad, 3) * 8];
        }
        #pragma unroll
        for (int mt = 0; mt < 4; mt++)
            #pragma unroll
            for (int nt = 0; nt < 4; nt++)
                acc[mt][nt] = __builtin_amdgcn_mfma_f32_16x16x32_bf16(a_h[mt], b_h[nt], acc[mt][nt], 0, 0, 0);
        __syncthreads();
    }
    #pragma unroll
    for (int mt = 0; mt < 4; mt++)
        #pragma unroll
        for (int r = 0; r < 4; r++) {
            float bv = -1e30f; int bi = 0;
            #pragma unroll
            for (int nt = 0; nt < 4; nt++) {
                float v = acc[mt][nt][r];
                int col = bn + wn * 64 + nt * 16 + c15;
                if (v > bv) { bv = v; bi = col; }
            }
            #pragma unroll
            for (int m = 1; m < 16; m <<= 1) {
                float ov = __shfl_xor(bv, m, 64);
                int   oi = __shfl_xor(bi, m, 64);
                if (ov > bv || (ov == bv && oi < bi)) { bv = ov; bi = oi; }
            }
            if (c15 == 0) {
                int row = wm * 64 + mt * 16 + quad * 4 + r;
                redv[row][wn] = bv; redi[row][wn] = bi;
            }
        }
    __syncthreads();
    if (tid < 128) {
        float v0 = redv[tid][0], v1 = redv[tid][1];
        int   i0 = redi[tid][0], i1 = redi[tid][1];
        bool t = (v1 > v0) || (v1 == v0 && i1 < i0);
        pval[(size_t)blockIdx.x * 4096 + bm + tid] = t ? v1 : v0;
        pidx[(size_t)blockIdx.x * 4096 + bm + tid] = t ? i1 : i0;
    }
}

// fused reduce for both halves + ssum zeroing
__global__ void simreduce2_kernel(const float* __restrict__ pval, const int* __restrict__ pidx,
                                  float* __restrict__ bv0, int* __restrict__ bi0,
                                  float* __restrict__ bv1, int* __restrict__ bi1,
                                  float* __restrict__ ssum)
{
    if (blockIdx.x == 0 && threadIdx.x < 2) ssum[threadIdx.x] = 0.f;
    const int n = blockIdx.x * 256 + threadIdx.x;
    float best = -1e30f; int besti = 0x7fffffff;
    for (int c = 0; c < 32; c++) {
        float v = pval[(size_t)c * 4096 + n]; int ix = pidx[(size_t)c * 4096 + n];
        if (v > best || (v == best && ix < besti)) { best = v; besti = ix; }
    }
    bv0[n] = best; bi0[n] = besti;
    best = -1e30f; besti = 0x7fffffff;
    for (int c = 32; c < 64; c++) {
        float v = pval[(size_t)c * 4096 + n]; int ix = pidx[(size_t)c * 4096 + n];
        if (v > best || (v == best && ix < besti)) { best = v; besti = ix; }
    }
    bv1[n] = best; bi1[n] = besti - 4096;
}

// ===================== conversions =====================
__global__ __launch_bounds__(256) void xconv_kernel(const float* __restrict__ s,
                                                    ushort* __restrict__ dh)
{
    const int i = blockIdx.x * 256 + threadIdx.x;
    float4 v = ((const float4*)s)[i];
    ushort4 h;
    h.x = f2bf(v.x); h.y = f2bf(v.y); h.z = f2bf(v.z); h.w = f2bf(v.w);
    ((ushort4*)dh)[i] = h;
}

__global__ __launch_bounds__(256) void wtrans_kernel(const float* __restrict__ src, int R, int Cc,
                                                     ushort* __restrict__ dh, ushort* __restrict__ dl)
{
    __shared__ float t[64][65];
    const int tid = threadIdx.x;
    const int c0 = blockIdx.x * 64, r0 = blockIdx.y * 64;
    #pragma unroll
    for (int i = 0; i < 16; i++) {
        int lin = i * 256 + tid;
        int rr = lin >> 6, cc = lin & 63;
        t[rr][cc] = src[(size_t)(r0 + rr) * Cc + c0 + cc];
    }
    __syncthreads();
    #pragma unroll
    for (int i = 0; i < 16; i++) {
        int lin = i * 256 + tid;
        int cc2 = lin >> 6, rr2 = lin & 63;
        float v = t[rr2][cc2];
        ushort h = f2bf(v);
        dh[(size_t)(c0 + cc2) * R + r0 + rr2] = h;
        if (dl) dl[(size_t)(c0 + cc2) * R + r0 + rr2] = f2bf(v - bf2f(h));
    }
}

// q: mh_rms -> bf16 [h][n][d]. one wave per (n,h)
__global__ __launch_bounds__(256) void qconv_kernel(const float* __restrict__ QKV,
                                                    const float* __restrict__ gamma_q,
                                                    ushort* __restrict__ Qh)
{
    const int wg = blockIdx.x * 4 + (threadIdx.x >> 6);
    const int lane = threadIdx.x & 63;
    const int n = wg >> 4, h = wg & 15;
    float x = QKV[(size_t)n * 3072 + h * 64 + lane];
    float ss = x * x;
    #pragma unroll
    for (int off = 32; off; off >>= 1) ss += __shfl_xor(ss, off, 64);
    float v = x * (8.0f * gamma_q[h * 64 + lane] / fmaxf(sqrtf(ss), 1e-12f));
    Qh[((size_t)h * 4096 + n) * 64 + lane] = f2bf(v);
}

// l2-normalize rows -> bf16, three sources in one launch. grid (4096, 3)
__global__ __launch_bounds__(256) void kbn3_kernel(const float* __restrict__ QKV,
                                                   const float* __restrict__ k0,
                                                   const float* __restrict__ k1,
                                                   ushort* __restrict__ kbn,
                                                   ushort* __restrict__ k01bn)
{
    const int n = blockIdx.x, t = threadIdx.x, y = blockIdx.y;
    const float* src; int ld; ushort* dst;
    if (y == 0)      { src = QKV + 1024; ld = 3072; dst = kbn; }
    else if (y == 1) { src = k0; ld = 1024; dst = k01bn; }
    else             { src = k1; ld = 1024; dst = k01bn + (size_t)4096 * 1024; }
    float4 v = *(const float4*)(src + (size_t)n * ld + 4 * t);
    float ss = v.x * v.x + v.y * v.y + v.z * v.z + v.w * v.w;
    #pragma unroll
    for (int off = 32; off; off >>= 1) ss += __shfl_xor(ss, off, 64);
    __shared__ float wsum[4];
    if ((t & 63) == 0) wsum[t >> 6] = ss;
    __syncthreads();
    float inv = 1.0f / fmaxf(sqrtf(wsum[0] + wsum[1] + wsum[2] + wsum[3]), 1e-12f);
    ushort4 o;
    o.x = f2bf(v.x * inv); o.y = f2bf(v.y * inv);
    o.z = f2bf(v.z * inv); o.w = f2bf(v.w * inv);
    *(ushort4*)(dst + (size_t)n * 1024 + 4 * t) = o;
}

// combine + per-head mh_rms(k) -> CKh [16][4096][64]; CV fp32 + sumsqs
__global__ __launch_bounds__(256) void combine_kernel(
    const float* __restrict__ QKV,
    const float* __restrict__ k0, const float* __restrict__ v0,
    const float* __restrict__ k1, const float* __restrict__ v1,
    const float* __restrict__ bv0, const int* __restrict__ bi0,
    const float* __restrict__ bv1, const int* __restrict__ bi1,
    const float* __restrict__ gamma_k,
    ushort* __restrict__ CKh,
    float* __restrict__ CV, float* __restrict__ ss)
{
    const int n = blockIdx.x, t = threadIdx.x;
    const bool va0 = bv0[n] > TAU_F; const int i0 = bi0[n];
    const bool va1 = bv1[n] > TAU_F; const int i1 = bi1[n];
    float4 kf = ((const float4*)(QKV + (size_t)n * 3072 + 1024))[t];
    float4 vf = ((const float4*)(QKV + (size_t)n * 3072 + 2048))[t];
    float4 kg0 = va0 ? ((const float4*)(k0 + (size_t)i0 * 1024))[t] : kf;
    float4 vg0 = va0 ? ((const float4*)(v0 + (size_t)i0 * 1024))[t] : vf;
    float4 kg1 = va1 ? ((const float4*)(k1 + (size_t)i1 * 1024))[t] : kf;
    float4 vg1 = va1 ? ((const float4*)(v1 + (size_t)i1 * 1024))[t] : vf;
    float4 ck, cv;
    ck.x = 0.5f * kg0.x + 0.5f * kg1.x + kf.x;
    ck.y = 0.5f * kg0.y + 0.5f * kg1.y + kf.y;
    ck.z = 0.5f * kg0.z + 0.5f * kg1.z + kf.z;
    ck.w = 0.5f * kg0.w + 0.5f * kg1.w + kf.w;
    cv.x = 0.5f * vg0.x + 0.5f * vg1.x + vf.x;
    cv.y = 0.5f * vg0.y + 0.5f * vg1.y + vf.y;
    cv.z = 0.5f * vg0.z + 0.5f * vg1.z + vf.z;
    cv.w = 0.5f * vg0.w + 0.5f * vg1.w + vf.w;
    ((float4*)(CV + (size_t)n * 1024))[t] = cv;
    float s0 = vf.x * vf.x + vf.y * vf.y + vf.z * vf.z + vf.w * vf.w;
    float s1 = cv.x * cv.x + cv.y * cv.y + cv.z * cv.z + cv.w * cv.w;
    #pragma unroll
    for (int off = 32; off; off >>= 1) {
        s0 += __shfl_xor(s0, off, 64);
        s1 += __shfl_xor(s1, off, 64);
    }
    __shared__ float w0[4], w1[4];
    if ((t & 63) == 0) { w0[t >> 6] = s0; w1[t >> 6] = s1; }
    float hs = ck.x * ck.x + ck.y * ck.y + ck.z * ck.z + ck.w * ck.w;
    #pragma unroll
    for (int m = 1; m < 16; m <<= 1) hs += __shfl_xor(hs, m, 64);
    float inv = 8.0f / fmaxf(sqrtf(hs), 1e-12f);
    float4 g = ((const float4*)gamma_k)[t];
    const int h = t >> 4;
    size_t o = ((size_t)h * 4096 + n) * 64 + 4 * (t & 15);
    ushort4 hh;
    hh.x = f2bf(ck.x * inv * g.x);
    hh.y = f2bf(ck.y * inv * g.y);
    hh.z = f2bf(ck.z * inv * g.z);
    hh.w = f2bf(ck.w * inv * g.w);
    *(ushort4*)(CKh + o) = hh;
    __syncthreads();
    if (t == 0) {
        atomicAdd(ss + 0, w0[0] + w0[1] + w0[2] + w0[3]);
        atomicAdd(ss + 1, w1[0] + w1[1] + w1[2] + w1[3]);
    }
}

// CV fp32 [4096][1024] --(*sv)--> Vt bf16 [1024][4096]
__global__ __launch_bounds__(256) void vt_kernel(const float* __restrict__ CV,
                                                 const float* __restrict__ ss,
                                                 ushort* __restrict__ Vt)
{
    __shared__ float t[64][65];
    const float sv = sqrtf(ss[0] / ss[1]);
    const int tid = threadIdx.x;
    const int n0 = blockIdx.x * 64, d0 = blockIdx.y * 64;
    #pragma unroll
    for (int i = 0; i < 16; i++) {
        int lin = i * 256 + tid;
        int r = lin >> 6, c = lin & 63;
        t[r][c] = CV[(size_t)(n0 + r) * 1024 + d0 + c];
    }
    __syncthreads();
    #pragma unroll
    for (int i = 0; i < 16; i++) {
        int lin = i * 256 + tid;
        int dr = lin >> 6, nc = lin & 63;
        Vt[(size_t)(d0 + dr) * 4096 + n0 + nc] = f2bf(t[nc][dr] * sv);
    }
}

// ===================== flash attention: staged LDS + fixed-max softmax =====================
// grid (64 q-tiles, 16 heads), 256 threads = 4 waves, 16 q-rows each.
// Fixed-max: |q|=|k|=8 per head (rms) => s/8 in [-8.1,8.1]; p=exp(s/8-8.5) <= 1 always,
// softmax identical after normalization => no online-max state, no rescale, l per-lane.
// Stage 128 keys of K (16KB) + V (16KB) per barrier pair; two 64-key sub-tiles between
// barriers. Ps (8KB) is wave-private rows => no barrier needed for it. LDS 40KB -> 4 blk/CU.
__global__ __launch_bounds__(256) void attn_mfma(
    const ushort* __restrict__ Qh,   // [16][4096][64]
    const ushort* __restrict__ Kh,   // [16][4096][64]
    const ushort* __restrict__ Vt,   // [16*64][4096]
    ushort* __restrict__ Hb)         // [4096][1024]
{
    __shared__ __align__(16) ushort Ks[128 * 64];   // 16 KB
    __shared__ __align__(16) ushort Vs[64 * 128];   // 16 KB
    __shared__ __align__(16) ushort Ps[64 * 64];    // 8 KB, wave-private rows
    const int h = blockIdx.y;
    const int n0 = blockIdx.x * 64;
    const int tid = threadIdx.x;
    const int w = tid >> 6, lane = tid & 63;
    const int quad = lane >> 4, c15 = lane & 15;

    short8 qf[2];
    #pragma unroll
    for (int kh = 0; kh < 2; kh++)
        qf[kh] = *(const short8*)(Qh + ((size_t)h * 4096 + n0 + w * 16 + c15) * 64 + kh * 32 + quad * 8);

    floatx4 po[4];
    #pragma unroll
    for (int nt = 0; nt < 4; nt++) po[nt] = (floatx4){0.f, 0.f, 0.f, 0.f};
    float lac[4] = {0.f, 0.f, 0.f, 0.f};

    for (int it = 0; it < 32; ++it) {
        const int m0 = it * 128;
        stage_swz<8, 16>(Ks, (const char*)(Kh + ((size_t)h * 4096 + m0) * 64), 128, w, lane);
        stage_swz<16, 16>(Vs, (const char*)(Vt + (size_t)h * 64 * 4096 + m0), 8192, w, lane);
        __syncthreads();

        #pragma unroll
        for (int sub = 0; sub < 2; ++sub) {
            // S = Q K^T from staged Ks
            floatx4 s[4];
            #pragma unroll
            for (int nt = 0; nt < 4; nt++) {
                int rk = sub * 64 + nt * 16 + c15;
                short8 ka = *(const short8*)&Ks[rk * 64 + swz(rk, quad, 7) * 8];
                short8 kb = *(const short8*)&Ks[rk * 64 + swz(rk, 4 + quad, 7) * 8];
                floatx4 z = (floatx4){0.f, 0.f, 0.f, 0.f};
                z = __builtin_amdgcn_mfma_f32_16x16x32_bf16(qf[0], ka, z, 0, 0, 0);
                z = __builtin_amdgcn_mfma_f32_16x16x32_bf16(qf[1], kb, z, 0, 0, 0);
                s[nt] = z;
            }
            // fixed-max numerators -> Ps (wave-private; in-wave lgkmcnt only)
            const int prow0 = w * 16 + quad * 4;
            #pragma unroll
            for (int nt = 0; nt < 4; nt++) {
                int col = nt * 16 + c15;
                #pragma unroll
                for (int r = 0; r < 4; r++) {
                    float p = __expf(fmaf(s[nt][r], 0.125f, -8.5f));
                    lac[r] += p;
                    int pr = prow0 + r;
                    Ps[pr * 64 + swz(pr, col >> 3, 7) * 8 + (col & 7)] = f2bf(p);
                }
            }
            // O += P V from staged Vs
            const int pr2 = w * 16 + c15;
            #pragma unroll
            for (int kb2 = 0; kb2 < 2; kb2++) {
                short8 pa = *(const short8*)&Ps[pr2 * 64 + swz(pr2, kb2 * 4 + quad, 7) * 8];
                #pragma unroll
                for (int nt = 0; nt < 4; nt++) {
                    int dr = nt * 16 + c15;
                    int j = sub * 8 + kb2 * 4 + quad;
                    short8 vb = *(const short8*)&Vs[dr * 128 + swz(dr, j, 15) * 8];
                    po[nt] = __builtin_amdgcn_mfma_f32_16x16x32_bf16(pa, vb, po[nt], 0, 0, 0);
                }
            }
        }
        __syncthreads();
    }
    // final l reduce (16 lanes per row) + normalize + store
    #pragma unroll
    for (int r = 0; r < 4; r++) {
        float l = lac[r];
        #pragma unroll
        for (int m = 1; m < 16; m <<= 1) l += __shfl_xor(l, m, 64);
        float inv = 1.0f / l;
        int row = n0 + w * 16 + quad * 4 + r;
        #pragma unroll
        for (int nt = 0; nt < 4; nt++)
            Hb[(size_t)row * 1024 + h * 64 + nt * 16 + c15] = f2bf(po[nt][r] * inv);
    }
}

// ===================== launcher =====================
extern "C" void kernel_launch(void* const* d_in, const int* in_sizes, int n_in,
                              void* d_out, int out_size, void* d_ws, size_t ws_size,
                              hipStream_t stream)
{
    const float* x       = (const float*)d_in[0];
    const float* k0      = (const float*)d_in[1];
    const float* v0      = (const float*)d_in[2];
    const float* k1      = (const float*)d_in[3];
    const float* v1      = (const float*)d_in[4];
    const float* W_qkv   = (const float*)d_in[5];
    const float* b_qkv   = (const float*)d_in[6];
    const float* gamma_q = (const float*)d_in[7];
    const float* gamma_k = (const float*)d_in[8];
    const float* W_out   = (const float*)d_in[9];
    const float* b_out   = (const float*)d_in[10];
    float* out = (float*)d_out;

    char* W = (char*)d_ws;
    float*  QKV = (float*)(W + 0);
    ushort* Vt  = (ushort*)(W + 0);
    ushort* Hb  = (ushort*)(W + 8388608);
    ushort* Qbh = (ushort*)(W + 50331648);
    ushort* xh   = (ushort*)(W + 67108864);
    ushort* Wqh  = (ushort*)(W + 67108864 + 8388608);
    ushort* kbn  = (ushort*)(W + 67108864);
    ushort* k01bn= (ushort*)(W + 67108864 + 8388608);
    float*  pval = (float*)(W + 67108864 + 25165824);
    int*    pidx = (int*)  (W + 67108864 + 26214400);
    float*  CV   = (float*)(W + 67108864);
    ushort* CKh  = (ushort*)(W + 67108864 + 16777216);
    ushort* Wob  = (ushort*)(W + 67108864);
    float* bv0  = (float*)(W + 100663296);
    int*   bi0  = (int*)  (W + 100663296 + 16384);
    float* bv1  = (float*)(W + 100663296 + 32768);
    int*   bi1  = (int*)  (W + 100663296 + 49152);
    float* ssum = (float*)(W + 100663296 + 65536);

    // 1. convert inputs for QKV GEMM (plain bf16)
    xconv_kernel<<<4096, 256, 0, stream>>>(x, xh);
    wtrans_kernel<<<dim3(48, 16), 256, 0, stream>>>(W_qkv, 1024, 3072, Wqh, nullptr);
    // 2. QKV = x @ W_qkv + b (plain bf16)
    gemm_nt_kernel<false><<<dim3(24, 32), 256, 0, stream>>>(xh, nullptr, 1024, Wqh, nullptr, 1024,
                                                            b_qkv, QKV, 3072, 1024);
    // 3. q -> mh_rms -> bf16 [h][n][d]
    qconv_kernel<<<16384, 256, 0, stream>>>(QKV, gamma_q, Qbh);
    // 4. normalized bf16 copies for sim
    kbn3_kernel<<<dim3(4096, 3), 256, 0, stream>>>(QKV, k0, k1, kbn, k01bn);
    // 5. sim + top-1 over concatenated [k0;k1]
    simmax_mfma<<<dim3(64, 32), 256, 0, stream>>>(kbn, k01bn, pval, pidx);
    simreduce2_kernel<<<16, 256, 0, stream>>>(pval, pidx, bv0, bi0, bv1, bi1, ssum);
    // 6. combine (+mh_rms k fused; sk cancels) -> CKh, CV fp32, sumsqs
    combine_kernel<<<4096, 256, 0, stream>>>(QKV, k0, v0, k1, v1, bv0, bi0, bv1, bi1,
                                             gamma_k, CKh, CV, ssum);
    // 7. V: scale by sv + transpose -> Vt bf16 [1024][4096]
    vt_kernel<<<dim3(64, 16), 256, 0, stream>>>(CV, ssum, Vt);
    // 8. W_out transpose -> bf16 (CV dead now)
    wtrans_kernel<<<dim3(16, 16), 256, 0, stream>>>(W_out, 1024, 1024, Wob, nullptr);
    // 9. flash attention (staged LDS, fixed-max softmax)
    attn_mfma<<<dim3(64, 16), 256, 0, stream>>>(Qbh, CKh, Vt, Hb);
    // 10. out = Hb @ W_out^T + b_out (plain bf16)
    gemm_nt_kernel<false><<<dim3(8, 32), 256, 0, stream>>>(Hb, nullptr, 1024, Wob, nullptr, 1024,
                                                           b_out, out, 1024, 1024);
}

// Round 7
// 525.176 us; speedup vs baseline: 1.7203x; 1.1110x over previous
//
#include <hip/hip_runtime.h>
#include <math.h>

#define TAU_F 0.6f

typedef short short8 __attribute__((ext_vector_type(8)));
typedef float floatx4 __attribute__((ext_vector_type(4)));
typedef int   intx4  __attribute__((ext_vector_type(4)));

__device__ __forceinline__ ushort f2bf(float f) {
    unsigned u = __float_as_uint(f);
    u += 0x7FFF + ((u >> 16) & 1);
    return (ushort)(u >> 16);
}
__device__ __forceinline__ float bf2f(ushort h) {
    return __uint_as_float(((unsigned)h) << 16);
}
__device__ __forceinline__ int swz(int row, int j, int mask) { return j ^ (row & mask); }

// Stage a tile from global into LDS with XOR-chunk swizzle via global_load_lds (16B).
// SC = number of 1KB superchunks; CPR = 16B chunks per row.
template<int CPR, int SC>
__device__ __forceinline__ void stage_swz(void* lds, const char* g, int rowstride_bytes,
                                          int w, int lane)
{
    #pragma unroll
    for (int p = 0; p < (SC + 3) / 4; ++p) {
        int sc = w + p * 4;
        if (SC % 4 != 0 && sc >= SC) break;
        int LC = sc * 64 + lane;
        int r = LC / CPR;
        int s = LC % CPR;
        int j = s ^ (r & (CPR - 1));
        const char* gp = g + (size_t)r * rowstride_bytes + j * 16;
        __builtin_amdgcn_global_load_lds(
            (const __attribute__((address_space(1))) void*)gp,
            (__attribute__((address_space(3))) void*)((char*)lds + sc * 1024), 16, 0, 0);
    }
}

// ===================== MFMA NT GEMM (bf16): C[M,N] = A[M,K] * Bt[N,K]^T + bias ==========
__global__ __launch_bounds__(256) void gemm_nt_kernel(
    const ushort* __restrict__ Ah, int lda,
    const ushort* __restrict__ Bh, int ldb,
    const float* __restrict__ bias, float* __restrict__ C, int ldc, int K)
{
    __shared__ __align__(16) ushort As_h[128 * 32];
    __shared__ __align__(16) ushort Bs_h[128 * 32];
    const int tid = threadIdx.x;
    const int w = tid >> 6, lane = tid & 63;
    const int quad = lane >> 4, c15 = lane & 15;
    const int wm = w >> 1, wn = w & 1;
    const int bm = blockIdx.y * 128, bn = blockIdx.x * 128;

    floatx4 acc[4][4];
    #pragma unroll
    for (int i = 0; i < 4; i++)
        #pragma unroll
        for (int j = 0; j < 4; j++) acc[i][j] = (floatx4){0.f, 0.f, 0.f, 0.f};

    const char* Ab = (const char*)(Ah + (size_t)bm * lda);
    const char* Bb = (const char*)(Bh + (size_t)bn * ldb);

    for (int k0 = 0; k0 < K; k0 += 32) {
        stage_swz<4, 8>(As_h, Ab + k0 * 2, lda * 2, w, lane);
        stage_swz<4, 8>(Bs_h, Bb + k0 * 2, ldb * 2, w, lane);
        __syncthreads();
        short8 a_h[4], b_h[4];
        #pragma unroll
        for (int mt = 0; mt < 4; mt++) {
            int row = wm * 64 + mt * 16 + c15;
            a_h[mt] = *(const short8*)&As_h[row * 32 + swz(row, quad, 3) * 8];
        }
        #pragma unroll
        for (int nt = 0; nt < 4; nt++) {
            int row = wn * 64 + nt * 16 + c15;
            b_h[nt] = *(const short8*)&Bs_h[row * 32 + swz(row, quad, 3) * 8];
        }
        #pragma unroll
        for (int mt = 0; mt < 4; mt++)
            #pragma unroll
            for (int nt = 0; nt < 4; nt++)
                acc[mt][nt] = __builtin_amdgcn_mfma_f32_16x16x32_bf16(a_h[mt], b_h[nt], acc[mt][nt], 0, 0, 0);
        __syncthreads();
    }
    #pragma unroll
    for (int mt = 0; mt < 4; mt++)
        #pragma unroll
        for (int nt = 0; nt < 4; nt++) {
            int col = bn + wn * 64 + nt * 16 + c15;
            float bs = bias ? bias[col] : 0.f;
            #pragma unroll
            for (int r = 0; r < 4; r++) {
                int row = bm + wm * 64 + mt * 16 + quad * 4 + r;
                C[(size_t)row * ldc + col] = acc[mt][nt][r] + bs;
            }
        }
}

// ===================== MFMA NT GEMM, 128x64 tile (for N-small GEMMs: more blocks) =========
__global__ __launch_bounds__(256) void gemm_nt64_kernel(
    const ushort* __restrict__ Ah, int lda,
    const ushort* __restrict__ Bh, int ldb,
    const float* __restrict__ bias, float* __restrict__ C, int ldc, int K)
{
    __shared__ __align__(16) ushort As_h[128 * 32];
    __shared__ __align__(16) ushort Bs_h[64 * 32];
    const int tid = threadIdx.x;
    const int w = tid >> 6, lane = tid & 63;
    const int quad = lane >> 4, c15 = lane & 15;
    const int wm = w >> 1, wn = w & 1;
    const int bm = blockIdx.y * 128, bn = blockIdx.x * 64;

    floatx4 acc[4][2];
    #pragma unroll
    for (int i = 0; i < 4; i++)
        #pragma unroll
        for (int j = 0; j < 2; j++) acc[i][j] = (floatx4){0.f, 0.f, 0.f, 0.f};

    const char* Ab = (const char*)(Ah + (size_t)bm * lda);
    const char* Bb = (const char*)(Bh + (size_t)bn * ldb);

    for (int k0 = 0; k0 < K; k0 += 32) {
        stage_swz<4, 8>(As_h, Ab + k0 * 2, lda * 2, w, lane);
        stage_swz<4, 4>(Bs_h, Bb + k0 * 2, ldb * 2, w, lane);
        __syncthreads();
        short8 a_h[4], b_h[2];
        #pragma unroll
        for (int mt = 0; mt < 4; mt++) {
            int row = wm * 64 + mt * 16 + c15;
            a_h[mt] = *(const short8*)&As_h[row * 32 + swz(row, quad, 3) * 8];
        }
        #pragma unroll
        for (int nt = 0; nt < 2; nt++) {
            int row = wn * 32 + nt * 16 + c15;
            b_h[nt] = *(const short8*)&Bs_h[row * 32 + swz(row, quad, 3) * 8];
        }
        #pragma unroll
        for (int mt = 0; mt < 4; mt++)
            #pragma unroll
            for (int nt = 0; nt < 2; nt++)
                acc[mt][nt] = __builtin_amdgcn_mfma_f32_16x16x32_bf16(a_h[mt], b_h[nt], acc[mt][nt], 0, 0, 0);
        __syncthreads();
    }
    #pragma unroll
    for (int mt = 0; mt < 4; mt++)
        #pragma unroll
        for (int nt = 0; nt < 2; nt++) {
            int col = bn + wn * 32 + nt * 16 + c15;
            float bs = bias ? bias[col] : 0.f;
            #pragma unroll
            for (int r = 0; r < 4; r++) {
                int row = bm + wm * 64 + mt * 16 + quad * 4 + r;
                C[(size_t)row * ldc + col] = acc[mt][nt][r] + bs;
            }
        }
}

// ===================== sim GEMM (int8, K=64 MFMA) with fused per-row max/argmax ==========
// A [4096][1024] i8, B [8192][1024] i8 (k0||k1), both rows pre-normalized+quantized x127.
__global__ __launch_bounds__(256) void simmax_i8(
    const char* __restrict__ A, const char* __restrict__ B,
    float* __restrict__ pval, int* __restrict__ pidx)
{
    __shared__ __align__(16) char As_b[128 * 64];
    __shared__ __align__(16) char Bs_b[128 * 64];
    __shared__ float redv[128][2];
    __shared__ int   redi[128][2];
    const int tid = threadIdx.x;
    const int w = tid >> 6, lane = tid & 63;
    const int quad = lane >> 4, c15 = lane & 15;
    const int wm = w >> 1, wn = w & 1;
    const int bm = blockIdx.y * 128, bn = blockIdx.x * 128;

    intx4 acc[4][4];
    #pragma unroll
    for (int i = 0; i < 4; i++)
        #pragma unroll
        for (int j = 0; j < 4; j++) acc[i][j] = (intx4){0, 0, 0, 0};

    const char* Ab = A + (size_t)bm * 1024;
    const char* Bb = B + (size_t)bn * 1024;

    for (int k0 = 0; k0 < 1024; k0 += 64) {
        stage_swz<4, 8>(As_b, Ab + k0, 1024, w, lane);
        stage_swz<4, 8>(Bs_b, Bb + k0, 1024, w, lane);
        __syncthreads();
        intx4 a_f[4], b_f[4];
        #pragma unroll
        for (int mt = 0; mt < 4; mt++) {
            int row = wm * 64 + mt * 16 + c15;
            a_f[mt] = *(const intx4*)&As_b[row * 64 + swz(row, quad, 3) * 16];
        }
        #pragma unroll
        for (int nt = 0; nt < 4; nt++) {
            int row = wn * 64 + nt * 16 + c15;
            b_f[nt] = *(const intx4*)&Bs_b[row * 64 + swz(row, quad, 3) * 16];
        }
        #pragma unroll
        for (int mt = 0; mt < 4; mt++)
            #pragma unroll
            for (int nt = 0; nt < 4; nt++)
                acc[mt][nt] = __builtin_amdgcn_mfma_i32_16x16x64_i8(a_f[mt], b_f[nt], acc[mt][nt], 0, 0, 0);
        __syncthreads();
    }
    const float isc = 1.0f / 16129.0f;   // 1/(127*127)
    #pragma unroll
    for (int mt = 0; mt < 4; mt++)
        #pragma unroll
        for (int r = 0; r < 4; r++) {
            float bv = -1e30f; int bi = 0;
            #pragma unroll
            for (int nt = 0; nt < 4; nt++) {
                float v = (float)acc[mt][nt][r] * isc;
                int col = bn + wn * 64 + nt * 16 + c15;
                if (v > bv) { bv = v; bi = col; }
            }
            #pragma unroll
            for (int m = 1; m < 16; m <<= 1) {
                float ov = __shfl_xor(bv, m, 64);
                int   oi = __shfl_xor(bi, m, 64);
                if (ov > bv || (ov == bv && oi < bi)) { bv = ov; bi = oi; }
            }
            if (c15 == 0) {
                int row = wm * 64 + mt * 16 + quad * 4 + r;
                redv[row][wn] = bv; redi[row][wn] = bi;
            }
        }
    __syncthreads();
    if (tid < 128) {
        float v0 = redv[tid][0], v1 = redv[tid][1];
        int   i0 = redi[tid][0], i1 = redi[tid][1];
        bool t = (v1 > v0) || (v1 == v0 && i1 < i0);
        pval[(size_t)blockIdx.x * 4096 + bm + tid] = t ? v1 : v0;
        pidx[(size_t)blockIdx.x * 4096 + bm + tid] = t ? i1 : i0;
    }
}

// fused reduce for both halves + ssum zeroing
__global__ void simreduce2_kernel(const float* __restrict__ pval, const int* __restrict__ pidx,
                                  float* __restrict__ bv0, int* __restrict__ bi0,
                                  float* __restrict__ bv1, int* __restrict__ bi1,
                                  float* __restrict__ ssum)
{
    if (blockIdx.x == 0 && threadIdx.x < 2) ssum[threadIdx.x] = 0.f;
    const int n = blockIdx.x * 256 + threadIdx.x;
    float best = -1e30f; int besti = 0x7fffffff;
    for (int c = 0; c < 32; c++) {
        float v = pval[(size_t)c * 4096 + n]; int ix = pidx[(size_t)c * 4096 + n];
        if (v > best || (v == best && ix < besti)) { best = v; besti = ix; }
    }
    bv0[n] = best; bi0[n] = besti;
    best = -1e30f; besti = 0x7fffffff;
    for (int c = 32; c < 64; c++) {
        float v = pval[(size_t)c * 4096 + n]; int ix = pidx[(size_t)c * 4096 + n];
        if (v > best || (v == best && ix < besti)) { best = v; besti = ix; }
    }
    bv1[n] = best; bi1[n] = besti - 4096;
}

// ===================== conversions =====================
__global__ __launch_bounds__(256) void xconv_kernel(const float* __restrict__ s,
                                                    ushort* __restrict__ dh)
{
    const int i = blockIdx.x * 256 + threadIdx.x;
    float4 v = ((const float4*)s)[i];
    ushort4 h;
    h.x = f2bf(v.x); h.y = f2bf(v.y); h.z = f2bf(v.z); h.w = f2bf(v.w);
    ((ushort4*)dh)[i] = h;
}

__global__ __launch_bounds__(256) void wtrans_kernel(const float* __restrict__ src, int R, int Cc,
                                                     ushort* __restrict__ dh)
{
    __shared__ float t[64][65];
    const int tid = threadIdx.x;
    const int c0 = blockIdx.x * 64, r0 = blockIdx.y * 64;
    #pragma unroll
    for (int i = 0; i < 16; i++) {
        int lin = i * 256 + tid;
        int rr = lin >> 6, cc = lin & 63;
        t[rr][cc] = src[(size_t)(r0 + rr) * Cc + c0 + cc];
    }
    __syncthreads();
    #pragma unroll
    for (int i = 0; i < 16; i++) {
        int lin = i * 256 + tid;
        int cc2 = lin >> 6, rr2 = lin & 63;
        dh[(size_t)(c0 + cc2) * R + r0 + rr2] = f2bf(t[rr2][cc2]);
    }
}

__device__ __forceinline__ char q127(float v) {
    float c = fminf(fmaxf(v * 127.0f, -127.0f), 127.0f);
    return (char)__float2int_rn(c);
}

// y=0..2: l2-normalize rows -> int8 (sim path). y=3: q mh_rms -> bf16 [h][n][d].
// grid (4096, 4), 256 threads.
__global__ __launch_bounds__(256) void prep_kernel(const float* __restrict__ QKV,
                                                   const float* __restrict__ k0,
                                                   const float* __restrict__ k1,
                                                   const float* __restrict__ gamma_q,
                                                   char* __restrict__ kq,       // [4096][1024] i8
                                                   char* __restrict__ k01q,     // [8192][1024] i8
                                                   ushort* __restrict__ Qbh)    // [16][4096][64]
{
    const int n = blockIdx.x, t = threadIdx.x, y = blockIdx.y;
    if (y == 3) {
        // q: per-head rms (16 lanes per head), write bf16 [h][n][d]
        float4 v = ((const float4*)(QKV + (size_t)n * 3072))[t];
        float hs = v.x * v.x + v.y * v.y + v.z * v.z + v.w * v.w;
        #pragma unroll
        for (int m = 1; m < 16; m <<= 1) hs += __shfl_xor(hs, m, 64);
        float inv = 8.0f / fmaxf(sqrtf(hs), 1e-12f);
        float4 g = ((const float4*)gamma_q)[t];
        const int h = t >> 4;
        size_t o = ((size_t)h * 4096 + n) * 64 + 4 * (t & 15);
        ushort4 hh;
        hh.x = f2bf(v.x * inv * g.x);
        hh.y = f2bf(v.y * inv * g.y);
        hh.z = f2bf(v.z * inv * g.z);
        hh.w = f2bf(v.w * inv * g.w);
        *(ushort4*)(Qbh + o) = hh;
        return;
    }
    const float* src; int ld; char* dst;
    if (y == 0)      { src = QKV + 1024; ld = 3072; dst = kq; }
    else if (y == 1) { src = k0; ld = 1024; dst = k01q; }
    else             { src = k1; ld = 1024; dst = k01q + (size_t)4096 * 1024; }
    float4 v = *(const float4*)(src + (size_t)n * ld + 4 * t);
    float ss = v.x * v.x + v.y * v.y + v.z * v.z + v.w * v.w;
    #pragma unroll
    for (int off = 32; off; off >>= 1) ss += __shfl_xor(ss, off, 64);
    __shared__ float wsum[4];
    if ((t & 63) == 0) wsum[t >> 6] = ss;
    __syncthreads();
    float inv = 1.0f / fmaxf(sqrtf(wsum[0] + wsum[1] + wsum[2] + wsum[3]), 1e-12f);
    char4 o;
    o.x = q127(v.x * inv); o.y = q127(v.y * inv);
    o.z = q127(v.z * inv); o.w = q127(v.w * inv);
    *(char4*)(dst + (size_t)n * 1024 + 4 * t) = o;
}

// combine + per-head mh_rms(k) -> CKh [16][4096][64]; CV fp32 + sumsqs
__global__ __launch_bounds__(256) void combine_kernel(
    const float* __restrict__ QKV,
    const float* __restrict__ k0, const float* __restrict__ v0,
    const float* __restrict__ k1, const float* __restrict__ v1,
    const float* __restrict__ bv0, const int* __restrict__ bi0,
    const float* __restrict__ bv1, const int* __restrict__ bi1,
    const float* __restrict__ gamma_k,
    ushort* __restrict__ CKh,
    float* __restrict__ CV, float* __restrict__ ss)
{
    const int n = blockIdx.x, t = threadIdx.x;
    const bool va0 = bv0[n] > TAU_F; const int i0 = bi0[n];
    const bool va1 = bv1[n] > TAU_F; const int i1 = bi1[n];
    float4 kf = ((const float4*)(QKV + (size_t)n * 3072 + 1024))[t];
    float4 vf = ((const float4*)(QKV + (size_t)n * 3072 + 2048))[t];
    float4 kg0 = va0 ? ((const float4*)(k0 + (size_t)i0 * 1024))[t] : kf;
    float4 vg0 = va0 ? ((const float4*)(v0 + (size_t)i0 * 1024))[t] : vf;
    float4 kg1 = va1 ? ((const float4*)(k1 + (size_t)i1 * 1024))[t] : kf;
    float4 vg1 = va1 ? ((const float4*)(v1 + (size_t)i1 * 1024))[t] : vf;
    float4 ck, cv;
    ck.x = 0.5f * kg0.x + 0.5f * kg1.x + kf.x;
    ck.y = 0.5f * kg0.y + 0.5f * kg1.y + kf.y;
    ck.z = 0.5f * kg0.z + 0.5f * kg1.z + kf.z;
    ck.w = 0.5f * kg0.w + 0.5f * kg1.w + kf.w;
    cv.x = 0.5f * vg0.x + 0.5f * vg1.x + vf.x;
    cv.y = 0.5f * vg0.y + 0.5f * vg1.y + vf.y;
    cv.z = 0.5f * vg0.z + 0.5f * vg1.z + vf.z;
    cv.w = 0.5f * vg0.w + 0.5f * vg1.w + vf.w;
    ((float4*)(CV + (size_t)n * 1024))[t] = cv;
    float s0 = vf.x * vf.x + vf.y * vf.y + vf.z * vf.z + vf.w * vf.w;
    float s1 = cv.x * cv.x + cv.y * cv.y + cv.z * cv.z + cv.w * cv.w;
    #pragma unroll
    for (int off = 32; off; off >>= 1) {
        s0 += __shfl_xor(s0, off, 64);
        s1 += __shfl_xor(s1, off, 64);
    }
    __shared__ float w0[4], w1[4];
    if ((t & 63) == 0) { w0[t >> 6] = s0; w1[t >> 6] = s1; }
    float hs = ck.x * ck.x + ck.y * ck.y + ck.z * ck.z + ck.w * ck.w;
    #pragma unroll
    for (int m = 1; m < 16; m <<= 1) hs += __shfl_xor(hs, m, 64);
    float inv = 8.0f / fmaxf(sqrtf(hs), 1e-12f);
    float4 g = ((const float4*)gamma_k)[t];
    const int h = t >> 4;
    size_t o = ((size_t)h * 4096 + n) * 64 + 4 * (t & 15);
    ushort4 hh;
    hh.x = f2bf(ck.x * inv * g.x);
    hh.y = f2bf(ck.y * inv * g.y);
    hh.z = f2bf(ck.z * inv * g.z);
    hh.w = f2bf(ck.w * inv * g.w);
    *(ushort4*)(CKh + o) = hh;
    __syncthreads();
    if (t == 0) {
        atomicAdd(ss + 0, w0[0] + w0[1] + w0[2] + w0[3]);
        atomicAdd(ss + 1, w1[0] + w1[1] + w1[2] + w1[3]);
    }
}

// CV fp32 [4096][1024] --(*sv)--> Vt bf16 [1024][4096]
__global__ __launch_bounds__(256) void vt_kernel(const float* __restrict__ CV,
                                                 const float* __restrict__ ss,
                                                 ushort* __restrict__ Vt)
{
    __shared__ float t[64][65];
    const float sv = sqrtf(ss[0] / ss[1]);
    const int tid = threadIdx.x;
    const int n0 = blockIdx.x * 64, d0 = blockIdx.y * 64;
    #pragma unroll
    for (int i = 0; i < 16; i++) {
        int lin = i * 256 + tid;
        int r = lin >> 6, c = lin & 63;
        t[r][c] = CV[(size_t)(n0 + r) * 1024 + d0 + c];
    }
    __syncthreads();
    #pragma unroll
    for (int i = 0; i < 16; i++) {
        int lin = i * 256 + tid;
        int dr = lin >> 6, nc = lin & 63;
        Vt[(size_t)(d0 + dr) * 4096 + n0 + nc] = f2bf(t[nc][dr] * sv);
    }
}

// ===================== flash attention: staged LDS + fixed-max softmax =====================
// grid (64 q-tiles, 16 heads), 256 threads = 4 waves, 16 q-rows each.
// Fixed-max: |q|=|k|=8 per head (rms) => s/8 in [-8.1,8.1]; p=exp(s/8-8.5) <= 1 always,
// softmax identical after normalization => no online-max state, no rescale, l per-lane.
__global__ __launch_bounds__(256) void attn_mfma(
    const ushort* __restrict__ Qh,   // [16][4096][64]
    const ushort* __restrict__ Kh,   // [16][4096][64]
    const ushort* __restrict__ Vt,   // [16*64][4096]
    ushort* __restrict__ Hb)         // [4096][1024]
{
    __shared__ __align__(16) ushort Ks[128 * 64];   // 16 KB
    __shared__ __align__(16) ushort Vs[64 * 128];   // 16 KB
    __shared__ __align__(16) ushort Ps[64 * 64];    // 8 KB, wave-private rows
    const int h = blockIdx.y;
    const int n0 = blockIdx.x * 64;
    const int tid = threadIdx.x;
    const int w = tid >> 6, lane = tid & 63;
    const int quad = lane >> 4, c15 = lane & 15;

    short8 qf[2];
    #pragma unroll
    for (int kh = 0; kh < 2; kh++)
        qf[kh] = *(const short8*)(Qh + ((size_t)h * 4096 + n0 + w * 16 + c15) * 64 + kh * 32 + quad * 8);

    floatx4 po[4];
    #pragma unroll
    for (int nt = 0; nt < 4; nt++) po[nt] = (floatx4){0.f, 0.f, 0.f, 0.f};
    float lac[4] = {0.f, 0.f, 0.f, 0.f};

    for (int it = 0; it < 32; ++it) {
        const int m0 = it * 128;
        stage_swz<8, 16>(Ks, (const char*)(Kh + ((size_t)h * 4096 + m0) * 64), 128, w, lane);
        stage_swz<16, 16>(Vs, (const char*)(Vt + (size_t)h * 64 * 4096 + m0), 8192, w, lane);
        __syncthreads();

        #pragma unroll
        for (int sub = 0; sub < 2; ++sub) {
            floatx4 s[4];
            #pragma unroll
            for (int nt = 0; nt < 4; nt++) {
                int rk = sub * 64 + nt * 16 + c15;
                short8 ka = *(const short8*)&Ks[rk * 64 + swz(rk, quad, 7) * 8];
                short8 kb = *(const short8*)&Ks[rk * 64 + swz(rk, 4 + quad, 7) * 8];
                floatx4 z = (floatx4){0.f, 0.f, 0.f, 0.f};
                z = __builtin_amdgcn_mfma_f32_16x16x32_bf16(qf[0], ka, z, 0, 0, 0);
                z = __builtin_amdgcn_mfma_f32_16x16x32_bf16(qf[1], kb, z, 0, 0, 0);
                s[nt] = z;
            }
            const int prow0 = w * 16 + quad * 4;
            #pragma unroll
            for (int nt = 0; nt < 4; nt++) {
                int col = nt * 16 + c15;
                #pragma unroll
                for (int r = 0; r < 4; r++) {
                    float p = __expf(fmaf(s[nt][r], 0.125f, -8.5f));
                    lac[r] += p;
                    int pr = prow0 + r;
                    Ps[pr * 64 + swz(pr, col >> 3, 7) * 8 + (col & 7)] = f2bf(p);
                }
            }
            const int pr2 = w * 16 + c15;
            #pragma unroll
            for (int kb2 = 0; kb2 < 2; kb2++) {
                short8 pa = *(const short8*)&Ps[pr2 * 64 + swz(pr2, kb2 * 4 + quad, 7) * 8];
                #pragma unroll
                for (int nt = 0; nt < 4; nt++) {
                    int dr = nt * 16 + c15;
                    int j = sub * 8 + kb2 * 4 + quad;
                    short8 vb = *(const short8*)&Vs[dr * 128 + swz(dr, j, 15) * 8];
                    po[nt] = __builtin_amdgcn_mfma_f32_16x16x32_bf16(pa, vb, po[nt], 0, 0, 0);
                }
            }
        }
        __syncthreads();
    }
    #pragma unroll
    for (int r = 0; r < 4; r++) {
        float l = lac[r];
        #pragma unroll
        for (int m = 1; m < 16; m <<= 1) l += __shfl_xor(l, m, 64);
        float inv = 1.0f / l;
        int row = n0 + w * 16 + quad * 4 + r;
        #pragma unroll
        for (int nt = 0; nt < 4; nt++)
            Hb[(size_t)row * 1024 + h * 64 + nt * 16 + c15] = f2bf(po[nt][r] * inv);
    }
}

// ===================== launcher =====================
extern "C" void kernel_launch(void* const* d_in, const int* in_sizes, int n_in,
                              void* d_out, int out_size, void* d_ws, size_t ws_size,
                              hipStream_t stream)
{
    const float* x       = (const float*)d_in[0];
    const float* k0      = (const float*)d_in[1];
    const float* v0      = (const float*)d_in[2];
    const float* k1      = (const float*)d_in[3];
    const float* v1      = (const float*)d_in[4];
    const float* W_qkv   = (const float*)d_in[5];
    const float* b_qkv   = (const float*)d_in[6];
    const float* gamma_q = (const float*)d_in[7];
    const float* gamma_k = (const float*)d_in[8];
    const float* W_out   = (const float*)d_in[9];
    const float* b_out   = (const float*)d_in[10];
    float* out = (float*)d_out;

    char* W = (char*)d_ws;
    // Region A (0..48M): QKV fp32; after combine reused for Vt + Hb
    float*  QKV = (float*)(W + 0);
    ushort* Vt  = (ushort*)(W + 0);
    ushort* Hb  = (ushort*)(W + 8388608);
    // Region B (48M..56M): Qb
    ushort* Qbh = (ushort*)(W + 50331648);
    // Region C (64M..96M): phased
    ushort* xh   = (ushort*)(W + 67108864);                 // 8 MB   (phase 1)
    ushort* Wqh  = (ushort*)(W + 67108864 + 8388608);       // 6 MB   (phase 1)
    char*   kq   = (char*)(W + 67108864);                   // 4 MB   (phase 2)
    char*   k01q = (char*)(W + 67108864 + 4194304);         // 8 MB   (phase 2)
    float*  pval = (float*)(W + 67108864 + 25165824);       // 1 MB
    int*    pidx = (int*)  (W + 67108864 + 26214400);       // 1 MB
    float*  CV   = (float*)(W + 67108864);                  // 16 MB  (phase 3)
    ushort* CKh  = (ushort*)(W + 67108864 + 16777216);      // 8 MB   (phase 3)
    ushort* Wob  = (ushort*)(W + 67108864);                 // 2 MB   (phase 4, CV dead)
    // Region D (96M..): small
    float* bv0  = (float*)(W + 100663296);
    int*   bi0  = (int*)  (W + 100663296 + 16384);
    float* bv1  = (float*)(W + 100663296 + 32768);
    int*   bi1  = (int*)  (W + 100663296 + 49152);
    float* ssum = (float*)(W + 100663296 + 65536);

    // 1. convert inputs for QKV GEMM (plain bf16)
    xconv_kernel<<<4096, 256, 0, stream>>>(x, xh);
    wtrans_kernel<<<dim3(48, 16), 256, 0, stream>>>(W_qkv, 1024, 3072, Wqh);
    // 2. QKV = x @ W_qkv + b (plain bf16)
    gemm_nt_kernel<<<dim3(24, 32), 256, 0, stream>>>(xh, 1024, Wqh, 1024,
                                                     b_qkv, QKV, 3072, 1024);
    // 3. prep: q mh_rms->bf16 [h][n][d] + i8-normalized rows for sim (one launch)
    prep_kernel<<<dim3(4096, 4), 256, 0, stream>>>(QKV, k0, k1, gamma_q, kq, k01q, Qbh);
    // 4. sim + top-1 over concatenated [k0;k1] (int8 MFMA, 2x rate)
    simmax_i8<<<dim3(64, 32), 256, 0, stream>>>(kq, k01q, pval, pidx);
    simreduce2_kernel<<<16, 256, 0, stream>>>(pval, pidx, bv0, bi0, bv1, bi1, ssum);
    // 5. combine (+mh_rms k fused; sk cancels) -> CKh, CV fp32, sumsqs
    combine_kernel<<<4096, 256, 0, stream>>>(QKV, k0, v0, k1, v1, bv0, bi0, bv1, bi1,
                                             gamma_k, CKh, CV, ssum);
    // 6. V: scale by sv + transpose -> Vt bf16 [1024][4096]
    vt_kernel<<<dim3(64, 16), 256, 0, stream>>>(CV, ssum, Vt);
    // 7. W_out transpose -> bf16 (CV dead now)
    wtrans_kernel<<<dim3(16, 16), 256, 0, stream>>>(W_out, 1024, 1024, Wob);
    // 8. flash attention (staged LDS, fixed-max softmax)
    attn_mfma<<<dim3(64, 16), 256, 0, stream>>>(Qbh, CKh, Vt, Hb);
    // 9. out = Hb @ W_out^T + b_out (128x64 tiles -> 512 blocks for occupancy)
    gemm_nt64_kernel<<<dim3(16, 32), 256, 0, stream>>>(Hb, 1024, Wob, 1024,
                                                       b_out, out, 1024, 1024);
}